// Round 5
// baseline (242.903 us; speedup 1.0000x reference)
//
#include <hip/hip_runtime.h>

#define DD 512
#define SCAN_B 256
#define BM 128
#define BK 32
typedef unsigned short u16;
typedef unsigned int u32;

typedef __attribute__((ext_vector_type(8))) __bf16 bf16v8;
typedef __attribute__((ext_vector_type(4))) float f32x4;
typedef __attribute__((ext_vector_type(4))) u32 u32x4;

__device__ __forceinline__ u16 f2bf(float f) {
  u32 u = __builtin_bit_cast(u32, f);
  u32 r = (u + 0x7fffu + ((u >> 16) & 1u)) >> 16;   // RNE
  return (u16)r;
}
__device__ __forceinline__ float bf2f(u32 h) {
  return __builtin_bit_cast(float, h << 16);
}

typedef const __attribute__((address_space(1))) void* gptr_t;
typedef __attribute__((address_space(3))) void* lptr_t;
__device__ __forceinline__ void gload_lds16(const void* g, void* l) {
  __builtin_amdgcn_global_load_lds((gptr_t)g, (lptr_t)l, 16, 0, 0);
}

// ---------------- W[k][n] f32 -> Wt[n][k] bf16 (LDS-tiled transpose) ----------------
__global__ __launch_bounds__(256) void wconv_t(const float* __restrict__ W,
                                               u16* __restrict__ Wt) {
  __shared__ float sm[64][65];
  const int bx = blockIdx.x;   // k tile
  const int by = blockIdx.y;   // n tile
  const int t = threadIdx.x;
  const int r = t >> 6;
  const int c = t & 63;
#pragma unroll
  for (int i = 0; i < 64; i += 4)
    sm[i + r][c] = W[(size_t)(bx * 64 + i + r) * DD + by * 64 + c];
  __syncthreads();
#pragma unroll
  for (int i = 0; i < 64; i += 4) {
    const int n = by * 64 + i + r;
    const int k = bx * 64 + c;
    Wt[(size_t)n * DD + k] = f2bf(sm[c][i + r]);
  }
}

// -------- fused GEMM: X[Mpad,512](bf16) = cast_bf16(A[M,512] f32) @ Wt^T --------
// BM=128 x BN=512 x BK=32; 512 threads (8 waves); wave w owns cols [w*64, w*64+64).
// A: reg-staged f32->bf16->ds_write (fuses the conversion pass, A read once).
// B: global_load_lds 16B direct. Both LDS tiles XOR-swizzled (2-way banking).
__global__ __launch_bounds__(512) void gemm_fused(const float* __restrict__ A,
                                                  const u16* __restrict__ Bt,
                                                  u16* __restrict__ X, int M) {
  __shared__ __align__(16) u16 ldsA[BM * BK];   // 8 KB
  __shared__ __align__(16) u16 ldsB[DD * BK];   // 32 KB
  const int tid = threadIdx.x;
  const int lane = tid & 63;
  const int w = tid >> 6;
  const int row0 = blockIdx.x * BM;

  const int lr = lane & 15;
  const int kg = lane >> 4;

  f32x4 acc[8][4] = {};

  // A staging: thread t <-> LDS chunk t (row=t>>2, slot kc=t&3, global gk = kc ^ ((row>>1)&3))
  const int arow = tid >> 2;
  const int agk = (tid & 3) ^ ((arow >> 1) & 3);
  const float* gA = A + (size_t)(row0 + arow) * DD + agk * 8;
  const bool a_ok = (row0 + arow) < M;
  u16* lA = &ldsA[tid * 8];

  // B staging: wave w issue q covers chunk c=(w*4+q)*64+lane
  const u16* gB[4];
  u16* lB[4];
#pragma unroll
  for (int q = 0; q < 4; ++q) {
    const int c = (w * 4 + q) * 64 + lane;
    const int col = c >> 2, kc = c & 3;
    const int gk = kc ^ ((col >> 1) & 3);
    gB[q] = Bt + (size_t)col * DD + gk * 8;
    lB[q] = &ldsB[c * 8];
  }

  for (int k0 = 0; k0 < DD; k0 += BK) {
#pragma unroll
    for (int q = 0; q < 4; ++q) gload_lds16(gB[q] + k0, lB[q]);

    f32x4 a0 = {0.f, 0.f, 0.f, 0.f}, a1 = {0.f, 0.f, 0.f, 0.f};
    if (a_ok) {
      a0 = __builtin_nontemporal_load((const f32x4*)(gA + k0));
      a1 = __builtin_nontemporal_load((const f32x4*)(gA + k0 + 4));
    }
    uint4 pk;
    pk.x = f2bf(a0.x) | ((u32)f2bf(a0.y) << 16);
    pk.y = f2bf(a0.z) | ((u32)f2bf(a0.w) << 16);
    pk.z = f2bf(a1.x) | ((u32)f2bf(a1.y) << 16);
    pk.w = f2bf(a1.z) | ((u32)f2bf(a1.w) << 16);
    *(uint4*)lA = pk;
    __syncthreads();   // drains vm (B gloads) + lgkm (A ds_write)

    bf16v8 af[8], bfr[4];
#pragma unroll
    for (int m = 0; m < 8; ++m) {
      const int row = m * 16 + lr;
      const int kc = kg ^ ((row >> 1) & 3);
      af[m] = *(const bf16v8*)&ldsA[row * BK + kc * 8];
    }
#pragma unroll
    for (int n = 0; n < 4; ++n) {
      const int col = w * 64 + n * 16 + lr;
      const int kc = kg ^ ((col >> 1) & 3);
      bfr[n] = *(const bf16v8*)&ldsB[col * BK + kc * 8];
    }
#pragma unroll
    for (int m = 0; m < 8; ++m)
#pragma unroll
      for (int n = 0; n < 4; ++n)
        acc[m][n] = __builtin_amdgcn_mfma_f32_16x16x32_bf16(af[m], bfr[n], acc[m][n], 0, 0, 0);
    __syncthreads();
  }

  // C/D layout: col = lane&15, row = (lane>>4)*4 + reg
  const int crow = (lane >> 4) * 4;
  const int ccol = lane & 15;
#pragma unroll
  for (int m = 0; m < 8; ++m) {
    const int rowb = row0 + m * 16 + crow;
#pragma unroll
    for (int n = 0; n < 4; ++n) {
      const int col = w * 64 + n * 16 + ccol;
#pragma unroll
      for (int r = 0; r < 4; ++r)
        X[(size_t)(rowb + r) * DD + col] = f2bf(acc[m][n][r]);
    }
  }
}

// ------------- zero masked rows of x (bf16) -------------
__global__ void zero_rows(u16* __restrict__ x, const int* __restrict__ mask) {
  const int r = mask[blockIdx.x];
  *(uint4*)(x + (size_t)r * DD + threadIdx.x * 8) = make_uint4(0, 0, 0, 0);
}

// ------------------------------ counting sort --------------------------------
__global__ __launch_bounds__(256) void hist(const int* __restrict__ dst,
                                            int* __restrict__ counts, int n) {
  const int i = blockIdx.x * blockDim.x + threadIdx.x;
  if (i < n) atomicAdd(&counts[dst[i]], 1);
}

__global__ __launch_bounds__(SCAN_B) void scanA(const int* __restrict__ counts,
                                                int* __restrict__ lscan,
                                                int* __restrict__ blockSums, int n) {
  __shared__ int sm[SCAN_B];
  const int t = threadIdx.x;
  const int i = blockIdx.x * SCAN_B + t;
  const int v = (i < n) ? counts[i] : 0;
  sm[t] = v;
  __syncthreads();
  for (int off = 1; off < SCAN_B; off <<= 1) {
    int add = (t >= off) ? sm[t - off] : 0;
    __syncthreads();
    sm[t] += add;
    __syncthreads();
  }
  if (i < n) lscan[i] = sm[t] - v;
  if (t == SCAN_B - 1) blockSums[blockIdx.x] = sm[t];
}

__global__ __launch_bounds__(SCAN_B) void scanB(int* __restrict__ blockSums, int nb) {
  __shared__ int sm[SCAN_B];
  const int t = threadIdx.x;
  const int v = (t < nb) ? blockSums[t] : 0;
  sm[t] = v;
  __syncthreads();
  for (int off = 1; off < SCAN_B; off <<= 1) {
    int add = (t >= off) ? sm[t - off] : 0;
    __syncthreads();
    sm[t] += add;
    __syncthreads();
  }
  if (t < nb) blockSums[t] = sm[t] - v;
}

__global__ __launch_bounds__(SCAN_B) void scanC(int* __restrict__ lscan,
                                                const int* __restrict__ blockBase,
                                                int* __restrict__ cursor, int n) {
  const int i = blockIdx.x * SCAN_B + threadIdx.x;
  if (i < n) {
    const int o = lscan[i] + blockBase[blockIdx.x];
    lscan[i] = o;
    cursor[i] = o;
  }
}

__global__ __launch_bounds__(256) void scatter_sort(const int* __restrict__ src,
                                                    const int* __restrict__ dst,
                                                    const float* __restrict__ ev,
                                                    int* __restrict__ cursor,
                                                    int* __restrict__ ssrc,
                                                    float* __restrict__ sval, int n) {
  const int i = blockIdx.x * blockDim.x + threadIdx.x;
  if (i < n) {
    const int pos = atomicAdd(&cursor[dst[i]], 1);
    ssrc[pos] = src[i];
    sval[pos] = ev[i];
  }
}

// ------------- per-node accumulation from bf16 x, f32 accumulate -------------
// one wave per node; nontemporal out stores keep x resident in L2/L3
__global__ __launch_bounds__(256) void aggregate(const u16* __restrict__ x,
                                                 const int* __restrict__ ssrc,
                                                 const float* __restrict__ sval,
                                                 const int* __restrict__ offsets,
                                                 const int* __restrict__ counts,
                                                 float* __restrict__ out, int n_nodes) {
  const int node = blockIdx.x * 4 + (threadIdx.x >> 6);
  if (node >= n_nodes) return;
  const int lane = threadIdx.x & 63;
  const int b = offsets[node];
  const int cnt = counts[node];
  float acc[8] = {};
  for (int j = 0; j < cnt; ++j) {
    const int s = __builtin_nontemporal_load(ssrc + b + j);
    const float v = __builtin_nontemporal_load(sval + b + j);
    const uint4 u = *(const uint4*)(x + (size_t)s * DD + lane * 8);
    acc[0] = fmaf(v, bf2f(u.x & 0xffffu), acc[0]);
    acc[1] = fmaf(v, bf2f(u.x >> 16),     acc[1]);
    acc[2] = fmaf(v, bf2f(u.y & 0xffffu), acc[2]);
    acc[3] = fmaf(v, bf2f(u.y >> 16),     acc[3]);
    acc[4] = fmaf(v, bf2f(u.z & 0xffffu), acc[4]);
    acc[5] = fmaf(v, bf2f(u.z >> 16),     acc[5]);
    acc[6] = fmaf(v, bf2f(u.w & 0xffffu), acc[6]);
    acc[7] = fmaf(v, bf2f(u.w >> 16),     acc[7]);
  }
  f32x4* o = (f32x4*)(out + (size_t)node * DD + lane * 8);
  f32x4 o0 = {acc[0], acc[1], acc[2], acc[3]};
  f32x4 o1 = {acc[4], acc[5], acc[6], acc[7]};
  __builtin_nontemporal_store(o0, o);
  __builtin_nontemporal_store(o1, o + 1);
}

__global__ void mask_tail(const int* __restrict__ mask, float* __restrict__ out_tail,
                          int nm) {
  const int i = blockIdx.x * blockDim.x + threadIdx.x;
  if (i < nm) out_tail[i] = (float)mask[i];
}

extern "C" void kernel_launch(void* const* d_in, const int* in_sizes, int n_in,
                              void* d_out, int out_size, void* d_ws, size_t ws_size,
                              hipStream_t stream) {
  const float* feat     = (const float*)d_in[0];
  const float* weight   = (const float*)d_in[1];
  const float* edge_val = (const float*)d_in[2];
  const int*   edge_src = (const int*)d_in[3];
  const int*   edge_dst = (const int*)d_in[4];
  const int*   mask_idx = (const int*)d_in[5];

  const int n_nodes = in_sizes[0] / DD;   // 50000
  const int n_edges = in_sizes[2];        // 400000
  const int n_mask  = in_sizes[5];        // 15000

  const int n_tiles_m = (n_nodes + BM - 1) / BM;   // 391
  const int m_pad = n_tiles_m * BM;                // 50048

  float* out = (float*)d_out;

  char* base = (char*)d_ws;
  size_t off = 0;
  auto alloc = [&](size_t bytes) {
    void* p = base + off;
    off = (off + bytes + 255) & ~(size_t)255;
    return p;
  };
  u16*   x      = (u16*)alloc((size_t)m_pad * DD * sizeof(u16));   // 51.3 MB
  u16*   wt     = (u16*)alloc((size_t)DD * DD * sizeof(u16));      // 0.5 MB
  int*   counts = (int*)alloc((size_t)n_nodes * sizeof(int));
  int*   offs   = (int*)alloc((size_t)n_nodes * sizeof(int));
  int*   cursor = (int*)alloc((size_t)n_nodes * sizeof(int));
  int*   bsums  = (int*)alloc(SCAN_B * sizeof(int));
  int*   ssrc   = (int*)alloc((size_t)n_edges * sizeof(int));
  float* sval   = (float*)alloc((size_t)n_edges * sizeof(float));

  const int nb = (n_nodes + SCAN_B - 1) / SCAN_B;  // 196

  // --- CSR build ---
  (void)hipMemsetAsync(counts, 0, (size_t)n_nodes * sizeof(int), stream);
  hist<<<(n_edges + 255) / 256, 256, 0, stream>>>(edge_dst, counts, n_edges);
  scanA<<<nb, SCAN_B, 0, stream>>>(counts, offs, bsums, n_nodes);
  scanB<<<1, SCAN_B, 0, stream>>>(bsums, nb);
  scanC<<<nb, SCAN_B, 0, stream>>>(offs, bsums, cursor, n_nodes);
  scatter_sort<<<(n_edges + 255) / 256, 256, 0, stream>>>(edge_src, edge_dst, edge_val,
                                                          cursor, ssrc, sval, n_edges);

  // --- W transpose+convert, then x = cast_bf16(feat) @ W fused ---
  dim3 wg(DD / 64, DD / 64);
  wconv_t<<<wg, 256, 0, stream>>>(weight, wt);
  gemm_fused<<<n_tiles_m, 512, 0, stream>>>(feat, wt, x, n_nodes);
  zero_rows<<<n_mask, 64, 0, stream>>>(x, mask_idx);

  // --- out[node] = sum val * x[src] ---
  aggregate<<<(n_nodes + 3) / 4, 256, 0, stream>>>(x, ssrc, sval, offs, counts, out, n_nodes);

  // --- output 1: mask_idx as float ---
  mask_tail<<<(n_mask + 255) / 256, 256, 0, stream>>>(mask_idx, out + (size_t)n_nodes * DD, n_mask);
}

// Round 6
// 232.922 us; speedup vs baseline: 1.0429x; 1.0429x over previous
//
#include <hip/hip_runtime.h>

#define DD 512
#define SCAN_B 256
#define BM 64
#define BK 32
#define NSTEP (DD / BK)
typedef unsigned short u16;
typedef unsigned int u32;

typedef __attribute__((ext_vector_type(8))) __bf16 bf16v8;
typedef __attribute__((ext_vector_type(4))) float f32x4;

__device__ __forceinline__ u16 f2bf(float f) {
  u32 u = __builtin_bit_cast(u32, f);
  u32 r = (u + 0x7fffu + ((u >> 16) & 1u)) >> 16;   // RNE
  return (u16)r;
}
__device__ __forceinline__ float bf2f(u32 h) {
  return __builtin_bit_cast(float, h << 16);
}

typedef const __attribute__((address_space(1))) void* gptr_t;
typedef __attribute__((address_space(3))) void* lptr_t;
__device__ __forceinline__ void gload_lds16(const void* g, void* l) {
  __builtin_amdgcn_global_load_lds((gptr_t)g, (lptr_t)l, 16, 0, 0);
}

// ---------------- W[k][n] f32 -> Wt[n][k] bf16 (LDS-tiled transpose) ----------------
__global__ __launch_bounds__(256) void wconv_t(const float* __restrict__ W,
                                               u16* __restrict__ Wt) {
  __shared__ float sm[64][65];
  const int bx = blockIdx.x;   // k tile
  const int by = blockIdx.y;   // n tile
  const int t = threadIdx.x;
  const int r = t >> 6;
  const int c = t & 63;
#pragma unroll
  for (int i = 0; i < 64; i += 4)
    sm[i + r][c] = W[(size_t)(bx * 64 + i + r) * DD + by * 64 + c];
  __syncthreads();
#pragma unroll
  for (int i = 0; i < 64; i += 4) {
    const int n = by * 64 + i + r;
    const int k = bx * 64 + c;
    Wt[(size_t)n * DD + k] = f2bf(sm[c][i + r]);
  }
}

// -------- fused GEMM: X[Mpad,512](bf16) = cast_bf16(A[M,512] f32) @ Wt^T --------
// BM=64 x BN=512 x BK=32; 256 threads (4 waves); wave w owns cols [w*128, w*128+128).
// Double-buffered LDS; 2-phase pipeline: stage(t+1) issued before MFMA(t).
// A: reg-staged f32->bf16->ds_write (fused conversion; A read once from HBM).
// B: global_load_lds 16B direct. Both LDS tiles XOR-swizzled (2-way banking).
__global__ __launch_bounds__(256) void gemm_fused(const float* __restrict__ A,
                                                  const u16* __restrict__ Bt,
                                                  u16* __restrict__ X, int M) {
  __shared__ __align__(16) u16 ldsA[2][BM * BK];   // 2 x 4 KB
  __shared__ __align__(16) u16 ldsB[2][DD * BK];   // 2 x 32 KB
  const int tid = threadIdx.x;
  const int lane = tid & 63;
  const int w = tid >> 6;          // 0..3
  const int row0 = blockIdx.x * BM;

  const int lr = lane & 15;
  const int kg = lane >> 4;

  f32x4 acc[4][8] = {};

  // A staging: thread t <-> chunk t (row=t>>2, slot kc=t&3, global gk=kc^((row>>1)&3))
  const int arow = tid >> 2;
  const int agk = (tid & 3) ^ ((arow >> 1) & 3);
  const float* gA = A + (size_t)(row0 + arow) * DD + agk * 8;
  const bool a_ok = (row0 + arow) < M;

  // B staging: wave w issue q covers chunk c=(w*8+q)*64+lane
  const u16* gB[8];
  int lBoff[8];
#pragma unroll
  for (int q = 0; q < 8; ++q) {
    const int c = (w * 8 + q) * 64 + lane;
    const int col = c >> 2, kc = c & 3;
    const int gk = kc ^ ((col >> 1) & 3);
    gB[q] = Bt + (size_t)col * DD + gk * 8;
    lBoff[q] = c * 8;
  }

  // ---- prologue: stage tile 0 into buf 0 ----
  {
    f32x4 a0 = {0.f, 0.f, 0.f, 0.f}, a1 = {0.f, 0.f, 0.f, 0.f};
#pragma unroll
    for (int q = 0; q < 8; ++q) gload_lds16(gB[q], &ldsB[0][lBoff[q]]);
    if (a_ok) {
      a0 = *(const f32x4*)(gA);
      a1 = *(const f32x4*)(gA + 4);
    }
    uint4 pk;
    pk.x = f2bf(a0.x) | ((u32)f2bf(a0.y) << 16);
    pk.y = f2bf(a0.z) | ((u32)f2bf(a0.w) << 16);
    pk.z = f2bf(a1.x) | ((u32)f2bf(a1.y) << 16);
    pk.w = f2bf(a1.z) | ((u32)f2bf(a1.w) << 16);
    *(uint4*)&ldsA[0][tid * 8] = pk;
  }
  __syncthreads();

  int cur = 0;
  for (int t = 0; t < NSTEP; ++t) {
    const int nxt = cur ^ 1;
    f32x4 a0 = {0.f, 0.f, 0.f, 0.f}, a1 = {0.f, 0.f, 0.f, 0.f};
    if (t < NSTEP - 1) {
      const int k1 = (t + 1) * BK;
#pragma unroll
      for (int q = 0; q < 8; ++q) gload_lds16(gB[q] + k1, &ldsB[nxt][lBoff[q]]);
      if (a_ok) {
        a0 = *(const f32x4*)(gA + k1);
        a1 = *(const f32x4*)(gA + k1 + 4);
      }
    }

    // compute from buf[cur]
    bf16v8 af[4], bfr[8];
#pragma unroll
    for (int m = 0; m < 4; ++m) {
      const int row = m * 16 + lr;
      const int kc = kg ^ ((row >> 1) & 3);
      af[m] = *(const bf16v8*)&ldsA[cur][row * BK + kc * 8];
    }
#pragma unroll
    for (int n = 0; n < 8; ++n) {
      const int col = w * 128 + n * 16 + lr;
      const int kc = kg ^ ((col >> 1) & 3);
      bfr[n] = *(const bf16v8*)&ldsB[cur][col * BK + kc * 8];
    }
#pragma unroll
    for (int m = 0; m < 4; ++m)
#pragma unroll
      for (int n = 0; n < 8; ++n)
        acc[m][n] = __builtin_amdgcn_mfma_f32_16x16x32_bf16(af[m], bfr[n], acc[m][n], 0, 0, 0);

    if (t < NSTEP - 1) {
      uint4 pk;
      pk.x = f2bf(a0.x) | ((u32)f2bf(a0.y) << 16);
      pk.y = f2bf(a0.z) | ((u32)f2bf(a0.w) << 16);
      pk.z = f2bf(a1.x) | ((u32)f2bf(a1.y) << 16);
      pk.w = f2bf(a1.z) | ((u32)f2bf(a1.w) << 16);
      *(uint4*)&ldsA[nxt][tid * 8] = pk;
    }
    __syncthreads();   // drains vm (B gloads) + lgkm (A ds_write) for buf[nxt]
    cur = nxt;
  }

  // C/D layout: col = lane&15, row = (lane>>4)*4 + reg
  const int crow = (lane >> 4) * 4;
  const int ccol = lane & 15;
#pragma unroll
  for (int m = 0; m < 4; ++m) {
    const int rowb = row0 + m * 16 + crow;
#pragma unroll
    for (int n = 0; n < 8; ++n) {
      const int col = w * 128 + n * 16 + ccol;
#pragma unroll
      for (int r = 0; r < 4; ++r)
        X[(size_t)(rowb + r) * DD + col] = f2bf(acc[m][n][r]);
    }
  }
}

// ------------- zero masked rows of x (bf16) -------------
__global__ void zero_rows(u16* __restrict__ x, const int* __restrict__ mask) {
  const int r = mask[blockIdx.x];
  *(uint4*)(x + (size_t)r * DD + threadIdx.x * 8) = make_uint4(0, 0, 0, 0);
}

// ------------------------------ counting sort --------------------------------
__global__ __launch_bounds__(256) void hist(const int* __restrict__ dst,
                                            int* __restrict__ counts, int n) {
  const int i = blockIdx.x * blockDim.x + threadIdx.x;
  if (i < n) atomicAdd(&counts[dst[i]], 1);
}

__global__ __launch_bounds__(SCAN_B) void scanA(const int* __restrict__ counts,
                                                int* __restrict__ lscan,
                                                int* __restrict__ blockSums, int n) {
  __shared__ int sm[SCAN_B];
  const int t = threadIdx.x;
  const int i = blockIdx.x * SCAN_B + t;
  const int v = (i < n) ? counts[i] : 0;
  sm[t] = v;
  __syncthreads();
  for (int off = 1; off < SCAN_B; off <<= 1) {
    int add = (t >= off) ? sm[t - off] : 0;
    __syncthreads();
    sm[t] += add;
    __syncthreads();
  }
  if (i < n) lscan[i] = sm[t] - v;
  if (t == SCAN_B - 1) blockSums[blockIdx.x] = sm[t];
}

__global__ __launch_bounds__(SCAN_B) void scanB(int* __restrict__ blockSums, int nb) {
  __shared__ int sm[SCAN_B];
  const int t = threadIdx.x;
  const int v = (t < nb) ? blockSums[t] : 0;
  sm[t] = v;
  __syncthreads();
  for (int off = 1; off < SCAN_B; off <<= 1) {
    int add = (t >= off) ? sm[t - off] : 0;
    __syncthreads();
    sm[t] += add;
    __syncthreads();
  }
  if (t < nb) blockSums[t] = sm[t] - v;
}

__global__ __launch_bounds__(SCAN_B) void scanC(int* __restrict__ lscan,
                                                const int* __restrict__ blockBase,
                                                int* __restrict__ cursor, int n) {
  const int i = blockIdx.x * SCAN_B + threadIdx.x;
  if (i < n) {
    const int o = lscan[i] + blockBase[blockIdx.x];
    lscan[i] = o;
    cursor[i] = o;
  }
}

__global__ __launch_bounds__(256) void scatter_sort(const int* __restrict__ src,
                                                    const int* __restrict__ dst,
                                                    const float* __restrict__ ev,
                                                    int* __restrict__ cursor,
                                                    int* __restrict__ ssrc,
                                                    float* __restrict__ sval, int n) {
  const int i = blockIdx.x * blockDim.x + threadIdx.x;
  if (i < n) {
    const int pos = atomicAdd(&cursor[dst[i]], 1);
    ssrc[pos] = src[i];
    sval[pos] = ev[i];
  }
}

// ------------- per-node accumulation from bf16 x, f32 accumulate -------------
// one wave per node, 4 nodes per 256-thread block (round-3 form: no nt hints)
__global__ __launch_bounds__(256) void aggregate(const u16* __restrict__ x,
                                                 const int* __restrict__ ssrc,
                                                 const float* __restrict__ sval,
                                                 const int* __restrict__ offsets,
                                                 const int* __restrict__ counts,
                                                 float* __restrict__ out, int n_nodes) {
  const int node = blockIdx.x * 4 + (threadIdx.x >> 6);
  if (node >= n_nodes) return;
  const int lane = threadIdx.x & 63;
  const int b = offsets[node];
  const int cnt = counts[node];
  float acc[8] = {};
  for (int j = 0; j < cnt; ++j) {
    const int s = ssrc[b + j];
    const float v = sval[b + j];
    const uint4 u = *(const uint4*)(x + (size_t)s * DD + lane * 8);
    acc[0] = fmaf(v, bf2f(u.x & 0xffffu), acc[0]);
    acc[1] = fmaf(v, bf2f(u.x >> 16),     acc[1]);
    acc[2] = fmaf(v, bf2f(u.y & 0xffffu), acc[2]);
    acc[3] = fmaf(v, bf2f(u.y >> 16),     acc[3]);
    acc[4] = fmaf(v, bf2f(u.z & 0xffffu), acc[4]);
    acc[5] = fmaf(v, bf2f(u.z >> 16),     acc[5]);
    acc[6] = fmaf(v, bf2f(u.w & 0xffffu), acc[6]);
    acc[7] = fmaf(v, bf2f(u.w >> 16),     acc[7]);
  }
  float4* o = (float4*)(out + (size_t)node * DD + lane * 8);
  o[0] = make_float4(acc[0], acc[1], acc[2], acc[3]);
  o[1] = make_float4(acc[4], acc[5], acc[6], acc[7]);
}

__global__ void mask_tail(const int* __restrict__ mask, float* __restrict__ out_tail,
                          int nm) {
  const int i = blockIdx.x * blockDim.x + threadIdx.x;
  if (i < nm) out_tail[i] = (float)mask[i];
}

extern "C" void kernel_launch(void* const* d_in, const int* in_sizes, int n_in,
                              void* d_out, int out_size, void* d_ws, size_t ws_size,
                              hipStream_t stream) {
  const float* feat     = (const float*)d_in[0];
  const float* weight   = (const float*)d_in[1];
  const float* edge_val = (const float*)d_in[2];
  const int*   edge_src = (const int*)d_in[3];
  const int*   edge_dst = (const int*)d_in[4];
  const int*   mask_idx = (const int*)d_in[5];

  const int n_nodes = in_sizes[0] / DD;   // 50000
  const int n_edges = in_sizes[2];        // 400000
  const int n_mask  = in_sizes[5];        // 15000

  const int n_tiles_m = (n_nodes + BM - 1) / BM;   // 782
  const int m_pad = n_tiles_m * BM;                // 50048

  float* out = (float*)d_out;

  char* base = (char*)d_ws;
  size_t off = 0;
  auto alloc = [&](size_t bytes) {
    void* p = base + off;
    off = (off + bytes + 255) & ~(size_t)255;
    return p;
  };
  u16*   x      = (u16*)alloc((size_t)m_pad * DD * sizeof(u16));   // 51.3 MB
  u16*   wt     = (u16*)alloc((size_t)DD * DD * sizeof(u16));      // 0.5 MB
  int*   counts = (int*)alloc((size_t)n_nodes * sizeof(int));
  int*   offs   = (int*)alloc((size_t)n_nodes * sizeof(int));
  int*   cursor = (int*)alloc((size_t)n_nodes * sizeof(int));
  int*   bsums  = (int*)alloc(SCAN_B * sizeof(int));
  int*   ssrc   = (int*)alloc((size_t)n_edges * sizeof(int));
  float* sval   = (float*)alloc((size_t)n_edges * sizeof(float));

  const int nb = (n_nodes + SCAN_B - 1) / SCAN_B;  // 196

  // --- CSR build ---
  (void)hipMemsetAsync(counts, 0, (size_t)n_nodes * sizeof(int), stream);
  hist<<<(n_edges + 255) / 256, 256, 0, stream>>>(edge_dst, counts, n_edges);
  scanA<<<nb, SCAN_B, 0, stream>>>(counts, offs, bsums, n_nodes);
  scanB<<<1, SCAN_B, 0, stream>>>(bsums, nb);
  scanC<<<nb, SCAN_B, 0, stream>>>(offs, bsums, cursor, n_nodes);
  scatter_sort<<<(n_edges + 255) / 256, 256, 0, stream>>>(edge_src, edge_dst, edge_val,
                                                          cursor, ssrc, sval, n_edges);

  // --- W transpose+convert, then x = cast_bf16(feat) @ W fused ---
  dim3 wg(DD / 64, DD / 64);
  wconv_t<<<wg, 256, 0, stream>>>(weight, wt);
  gemm_fused<<<n_tiles_m, 256, 0, stream>>>(feat, wt, x, n_nodes);
  zero_rows<<<n_mask, 64, 0, stream>>>(x, mask_idx);

  // --- out[node] = sum val * x[src] ---
  aggregate<<<(n_nodes + 3) / 4, 256, 0, stream>>>(x, ssrc, sval, offs, counts, out, n_nodes);

  // --- output 1: mask_idx as float ---
  mask_tail<<<(n_mask + 255) / 256, 256, 0, stream>>>(mask_idx, out + (size_t)n_nodes * DD, n_mask);
}